// Round 1
// 600.355 us; speedup vs baseline: 1.0112x; 1.0112x over previous
//
#include <hip/hip_runtime.h>
#include <hip/hip_bf16.h>
#include <math.h>

// Problem constants (B, I, H) = (16384, 1024, 1024); K = I + H = 2048.
#define B_SZ 16384
#define H_SZ 1024
#define K_SZ 2048
#define OUT_PLANE ((size_t)B_SZ * H_SZ)   // 16777216

// 256x256 effective GEMM tile: 256 b-rows x 64 h-cols x 4 gates.
// 512 threads = 8 waves (2 M-waves x 4 N-waves); 8-phase-style schedule,
// double-buffered 128 KiB LDS, counted vmcnt (never 0 in main loop).
#define BM 256
#define BNH 64
#define BK 64
#define NKT (K_SZ / BK)   // 32 K-tiles

typedef __bf16 bf16;
typedef __attribute__((ext_vector_type(8))) __bf16 bf16x8;
typedef __attribute__((ext_vector_type(4))) float floatx4;

__device__ __forceinline__ void gload_lds16(const bf16* g, bf16* l) {
    // async global->LDS, 16B per lane; LDS dest is wave-uniform base + lane*16
    __builtin_amdgcn_global_load_lds(
        (const __attribute__((address_space(1))) void*)g,
        (__attribute__((address_space(3))) void*)l, 16, 0, 0);
}

__device__ __forceinline__ void bar() { asm volatile("s_barrier" ::: "memory"); }
#define WAIT_VM(n) asm volatile("s_waitcnt vmcnt(" #n ")" ::: "memory")

__device__ __forceinline__ float sigmoidf_fast(float x) {
    return 1.f / (1.f + __expf(-x));
}
__device__ __forceinline__ float tanhf_fast(float x) {
    return 2.f / (1.f + __expf(-2.f * x)) - 1.f;
}

// ---- fused fp32->bf16 pack: X = [incoming | old_h] (B x 2048),
//      W = [Wi | Wh] per (gate,h) row (4096 x 2048) ----
__global__ void cvt_all(const float* __restrict__ inc, const float* __restrict__ oh,
                        const float* __restrict__ Wi, const float* __restrict__ Wh,
                        bf16* __restrict__ X, bf16* __restrict__ W) {
    const size_t nX = (size_t)B_SZ * K_SZ;
    size_t t  = (size_t)blockIdx.x * blockDim.x + threadIdx.x;
    size_t e0 = t * 8;                 // 8 elems/thread, never straddles k=1024
    const float* src;
    bf16* dst;
    if (e0 < nX) {
        size_t b = e0 >> 11;
        int    k = (int)(e0 & 2047);
        src = (k < 1024) ? (inc + b * 1024 + k) : (oh + b * 1024 + (k - 1024));
        dst = X + e0;
    } else {
        size_t e = e0 - nX;
        size_t n = e >> 11;
        int    k = (int)(e & 2047);
        src = (k < 1024) ? (Wi + n * 1024 + k) : (Wh + n * 1024 + (k - 1024));
        dst = W + e;
    }
    floatx4 f0 = *(const floatx4*)src;
    floatx4 f1 = *(const floatx4*)(src + 4);
    bf16x8 o;
    o[0]=(bf16)f0[0]; o[1]=(bf16)f0[1]; o[2]=(bf16)f0[2]; o[3]=(bf16)f0[3];
    o[4]=(bf16)f1[0]; o[5]=(bf16)f1[1]; o[6]=(bf16)f1[2]; o[7]=(bf16)f1[3];
    *(bf16x8*)dst = o;
}

// Staging helpers. A-half h = rows {h*64..h*64+63} U {128+h*64..+63}
// (aligned with wave-M quadrants). B rows rb = g*64 + j <-> W row g*1024+h0+j;
// B-half hb = gates {2hb, 2hb+1}. Each call = 2 global_load_lds per lane.
// Chunk-XOR swizzle is applied on the GLOBAL k-offset (gch baked into xg/wg);
// LDS destination stays linear (global_load_lds constraint).
__device__ __forceinline__ void stageA(const bf16* xg, bf16* dst, int h, int ktn, int wv) {
    gload_lds16(xg + (size_t)(h * 64) * K_SZ + ktn, dst + (h * 64 + wv * 8) * BK);
    gload_lds16(xg + (size_t)(128 + h * 64) * K_SZ + ktn, dst + (128 + h * 64 + wv * 8) * BK);
}
__device__ __forceinline__ void stageB(const bf16* wg, bf16* dst, int hb, int ktn, int wv) {
    gload_lds16(wg + (size_t)((2 * hb) * 1024) * K_SZ + ktn, dst + ((2 * hb) * 64 + wv * 8) * BK);
    gload_lds16(wg + (size_t)((2 * hb + 1) * 1024) * K_SZ + ktn, dst + ((2 * hb + 1) * 64 + wv * 8) * BK);
}

// ---- fused GEMM + LSTM epilogue, 8-phase schedule ----
__global__ __launch_bounds__(512, 2) void lstm_gemm(
    const bf16* __restrict__ X, const bf16* __restrict__ W,
    const float* __restrict__ bi, const float* __restrict__ oldc,
    float* __restrict__ out) {
    __shared__ bf16 As[2][BM * BK];   // 2 x 32 KiB
    __shared__ bf16 Bs[2][BM * BK];   // 2 x 32 KiB  (rows: g*64 + h-offset)

    const int tid  = threadIdx.x;
    const int lane = tid & 63;
    const int wv   = tid >> 6;        // 0..7
    const int wm   = wv >> 2;         // 0..1: M-half of output tile
    const int wn   = wv & 3;          // 0..3: 16-h group
    const int q    = lane >> 4;       // 0..3
    const int r16  = lane & 15;
    const int lrow = lane >> 3;       // 0..7
    const int gch  = (lane & 7) ^ lrow;   // swizzled global 16B k-chunk

    // XCD-bijective swizzle: 1024 blocks, 8 XCDs, 128 ids/XCD chunk.
    // Within a chunk bx varies fastest -> 16 blocks share one X panel in L2.
    const int id = blockIdx.y * 16 + blockIdx.x;
    const int sw = (id & 7) * 128 + (id >> 3);
    const int h0    = (sw & 15) * BNH;
    const int brow0 = (sw >> 4) * BM;

    const bf16* xg = X + (size_t)(brow0 + wv * 8 + lrow) * K_SZ + gch * 8;
    const bf16* wg = W + (size_t)(h0 + wv * 8 + lrow) * K_SZ + gch * 8;

    floatx4 acc[8][4];
    #pragma unroll
    for (int mg = 0; mg < 8; ++mg)
        #pragma unroll
        for (int g = 0; g < 4; ++g) {
            floatx4 z = {0.f, 0.f, 0.f, 0.f};
            acc[mg][g] = z;
        }

    bf16x8 Af[4][2];   // A frags for current M-quadrant: m x ks
    bf16x8 Bf[4][2];   // B frags for all 4 gates: g x ks

#define LDA(mh) do { \
    _Pragma("unroll") for (int m = 0; m < 4; ++m) { \
        const int row = wm * 128 + (mh) * 64 + m * 16 + r16; \
        const bf16* base = rA + (size_t)row * BK; \
        _Pragma("unroll") for (int ks = 0; ks < 2; ++ks) \
            Af[m][ks] = *(const bf16x8*)(base + (((ks * 4 + q) ^ (row & 7)) * 8)); \
    } } while (0)

#define LDB(nh) do { \
    _Pragma("unroll") for (int gg = 0; gg < 2; ++gg) { \
        const int row = ((nh) * 2 + gg) * 64 + wn * 16 + r16; \
        const bf16* base = rB + (size_t)row * BK; \
        _Pragma("unroll") for (int ks = 0; ks < 2; ++ks) \
            Bf[(nh) * 2 + gg][ks] = *(const bf16x8*)(base + (((ks * 4 + q) ^ (row & 7)) * 8)); \
    } } while (0)

#define MMA(mh, nh) do { \
    __builtin_amdgcn_s_setprio(1); \
    _Pragma("unroll") for (int m = 0; m < 4; ++m) \
    _Pragma("unroll") for (int gg = 0; gg < 2; ++gg) \
    _Pragma("unroll") for (int ks = 0; ks < 2; ++ks) \
        acc[(mh) * 4 + m][(nh) * 2 + gg] = __builtin_amdgcn_mfma_f32_16x16x32_bf16( \
            Af[m][ks], Bf[(nh) * 2 + gg][ks], acc[(mh) * 4 + m][(nh) * 2 + gg], 0, 0, 0); \
    __builtin_amdgcn_s_setprio(0); \
} while (0)

    const bf16* rA = As[0];
    const bf16* rB = Bs[0];
    bf16* wAp = As[1];
    bf16* wBp = Bs[1];

    // Prologue: stage tile 0 into buffer 0.  Issue order A0,B0,B1,A1 matches
    // the quadrant read order, so every main-loop wait is vmcnt(4).
    stageA(xg, As[0], 0, 0, wv);
    stageB(wg, Bs[0], 0, 0, wv);
    stageB(wg, Bs[0], 1, 0, wv);
    stageA(xg, As[0], 1, 0, wv);

    for (int t = 0; t < NKT - 1; ++t) {
        const int ktn = (t + 1) * BK;
        // p0: quadrant (M0, gates01). Needs A-half0 + B-half0 (oldest 4 loads).
        WAIT_VM(4); bar();
        LDA(0); LDB(0);
        stageA(xg, wAp, 0, ktn, wv);
        MMA(0, 0);
        bar();
        // p1: quadrant (M0, gates23). Needs B-half1.
        WAIT_VM(4); bar();
        LDB(1);
        stageB(wg, wBp, 0, ktn, wv);
        MMA(0, 1);
        bar();
        // p2: quadrant (M1, gates23). Needs A-half1.
        WAIT_VM(4); bar();
        LDA(1);
        stageB(wg, wBp, 1, ktn, wv);
        MMA(1, 1);
        bar();
        // p3: quadrant (M1, gates01). All operands already in registers.
        stageA(xg, wAp, 1, ktn, wv);
        MMA(1, 0);
        bar();
        // swap read/write buffers
        const bf16* tA = rA; rA = wAp; wAp = (bf16*)tA;
        const bf16* tB = rB; rB = wBp; wBp = (bf16*)tB;
    }

    // Peeled last K-tile (no staging): drain progressively.
    WAIT_VM(4); bar();
    LDA(0); LDB(0);
    MMA(0, 0);
    bar();
    WAIT_VM(2); bar();
    LDB(1);
    MMA(0, 1);
    bar();
    WAIT_VM(0); bar();
    LDA(1);
    MMA(1, 1);
    bar();
    MMA(1, 0);

#undef LDA
#undef LDB
#undef MMA

    // ---- fused epilogue: all 4 gates for (b,h) live in this lane ----
    float* outh  = out;
    float* outh2 = out + OUT_PLANE;
    float* outc  = out + 2 * OUT_PLANE;
    const int h = h0 + wn * 16 + r16;
    const float b_i = bi[h];
    const float b_f = bi[H_SZ + h];
    const float b_g = bi[2 * H_SZ + h];
    const float b_o = bi[3 * H_SZ + h];
    #pragma unroll
    for (int mg = 0; mg < 8; ++mg) {
        const int brow = brow0 + wm * 128 + mg * 16 + q * 4;
        #pragma unroll
        for (int rr = 0; rr < 4; ++rr) {
            const size_t idx = (size_t)(brow + rr) * H_SZ + h;
            float gi = acc[mg][0][rr] + b_i;
            float gf = acc[mg][1][rr] + b_f;
            float gv_ = acc[mg][2][rr] + b_g;
            float go = acc[mg][3][rr] + b_o;
            float iv = sigmoidf_fast(gi);
            float fv = sigmoidf_fast(gf);
            float gv = tanhf_fast(gv_);
            float ov = sigmoidf_fast(go);
            float c  = fv * oldc[idx] + iv * gv;
            float hv = ov * tanhf_fast(c);
            outh[idx]  = hv;
            outh2[idx] = hv;
            outc[idx]  = c;
        }
    }
}

// ---- insurance fallback if d_ws is too small for the bf16 pack (slow, fp32) ----
__global__ void lstm_fallback(const float* __restrict__ X, const float* __restrict__ Ho,
                              const float* __restrict__ Co, const float* __restrict__ Wi,
                              const float* __restrict__ bi, const float* __restrict__ Wh,
                              float* __restrict__ out) {
    int b = blockIdx.x;
    __shared__ float xs[1024], hs[1024];
    for (int k = threadIdx.x; k < 1024; k += blockDim.x) {
        xs[k] = X[(size_t)b * 1024 + k];
        hs[k] = Ho[(size_t)b * 1024 + k];
    }
    __syncthreads();
    for (int h = threadIdx.x; h < 1024; h += blockDim.x) {
        float g[4];
        for (int gg = 0; gg < 4; ++gg) {
            const float* wi = Wi + ((size_t)gg * 1024 + h) * 1024;
            const float* wh = Wh + ((size_t)gg * 1024 + h) * 1024;
            float acc = bi[gg * 1024 + h];
            for (int k = 0; k < 1024; ++k) acc += xs[k] * wi[k] + hs[k] * wh[k];
            g[gg] = acc;
        }
        float iv = sigmoidf_fast(g[0]);
        float fv = sigmoidf_fast(g[1]);
        float gv = tanhf_fast(g[2]);
        float ov = sigmoidf_fast(g[3]);
        float c  = fv * Co[(size_t)b * 1024 + h] + iv * gv;
        float hv = ov * tanhf_fast(c);
        size_t idx = (size_t)b * 1024 + h;
        out[idx] = hv;
        out[OUT_PLANE + idx] = hv;
        out[2 * OUT_PLANE + idx] = c;
    }
}

extern "C" void kernel_launch(void* const* d_in, const int* in_sizes, int n_in,
                              void* d_out, int out_size, void* d_ws, size_t ws_size,
                              hipStream_t stream) {
    const float* incoming = (const float*)d_in[0];
    const float* old_h    = (const float*)d_in[1];
    const float* old_c    = (const float*)d_in[2];
    const float* Wi       = (const float*)d_in[3];
    const float* bi       = (const float*)d_in[4];
    const float* Wh       = (const float*)d_in[5];
    float* out = (float*)d_out;

    const size_t nX = (size_t)B_SZ * K_SZ;       // bf16 elems
    const size_t nW = (size_t)4 * H_SZ * K_SZ;   // bf16 elems
    if (ws_size < (nX + nW) * sizeof(bf16)) {
        lstm_fallback<<<B_SZ, 256, 0, stream>>>(incoming, old_h, old_c, Wi, bi, Wh, out);
        return;
    }
    bf16* X = (bf16*)d_ws;
    bf16* W = X + nX;

    const int cvt_blocks = (int)((nX + nW) / 8 / 256);   // 20480
    cvt_all<<<cvt_blocks, 256, 0, stream>>>(incoming, old_h, Wi, Wh, X, W);

    dim3 grid(H_SZ / BNH, B_SZ / BM);   // (16, 64) = 1024 blocks
    lstm_gemm<<<grid, 512, 0, stream>>>(X, W, bi, old_c, out);
}